// Round 1
// baseline (585.860 us; speedup 1.0000x reference)
//
#include <hip/hip_runtime.h>

namespace {
constexpr int I_N   = 512;
constexpr int R_N   = 16384;
constexpr int NTOT  = I_N + R_N;      // 16896
constexpr int M     = 64;
constexpr int S     = 16;
constexpr int NW    = NTOT / 32;      // 528 state words
constexpr int ZW    = NW;             // always-zero word index (masked neighbors)
constexpr int BOFF  = 576;            // word offset of buffer B in LDS
constexpr int LDSW  = BOFF + NW + 16; // 1120 words
constexpr int N_OUT = 10;

// workspace layout (bytes)
constexpr size_t OFF_ADJ = 0;                         // N*8 u32 = 540672
constexpr size_t OFF_LUT = 540672;                    // N*8 u32 = 540672
constexpr size_t OFF_WPK = OFF_LUT + 540672;          // 1024 u32
constexpr size_t OFF_XPK = OFF_WPK + 4096;            // 2048 u32
constexpr size_t OFF_SPK = OFF_XPK + 8192;            // 529 u32 (+pad)
}

// ---- prep: pack LUT rows to bits, pre-decode adjacency into {byte_addr|shift<<16} ----
__global__ __launch_bounds__(256) void prep_big(
    const int* __restrict__ adj, const int* __restrict__ deg,
    const float* __restrict__ lut, unsigned* __restrict__ adjenc,
    unsigned* __restrict__ lutpk)
{
  int gid = blockIdx.x * 256 + threadIdx.x;
  if (gid >= NTOT * 8) return;
  int n = gid >> 3, k = gid & 7;
  unsigned a = (unsigned)adj[gid];
  // masked neighbors point at the always-zero word: bit contribution = 0
  unsigned e = (k < deg[n]) ? (((a >> 5) << 2) | ((a & 31u) << 16))
                            : (unsigned)(ZW * 4);
  adjenc[gid] = e;
  const float4* lp = reinterpret_cast<const float4*>(lut + (size_t)n * 256 + k * 32);
  unsigned w = 0;
  #pragma unroll
  for (int j = 0; j < 8; ++j) {
    float4 v = lp[j];
    w |= (v.x > 0.5f ? 1u : 0u) << (4 * j + 0);
    w |= (v.y > 0.5f ? 1u : 0u) << (4 * j + 1);
    w |= (v.z > 0.5f ? 1u : 0u) << (4 * j + 2);
    w |= (v.w > 0.5f ? 1u : 0u) << (4 * j + 3);
  }
  lutpk[gid] = w;
}

// ---- prep: pack w_in columns, x words, initial state words ----
__global__ __launch_bounds__(256) void prep_small(
    const float* __restrict__ x, const float* __restrict__ w_in,
    const float* __restrict__ init, unsigned* __restrict__ wpk,
    unsigned* __restrict__ xpk, unsigned* __restrict__ spk)
{
  int gid = blockIdx.x * 256 + threadIdx.x;
  if (gid < 1024) {                       // wpk[c*512+i], bit b = w_in[c*32+b][i]
    int c = gid >> 9, i = gid & 511;
    unsigned w = 0;
    for (int b = 0; b < 32; ++b)
      w |= (w_in[(c * 32 + b) * 512 + i] > 0.5f ? 1u : 0u) << b;
    wpk[gid] = w;
  } else if (gid < 3072) {                // xpk[(m*S+s)*2+c], bit b = x[m,s,c,b]
    int j = gid - 1024;
    const float* xp = x + (size_t)j * 32;
    unsigned w = 0;
    for (int b = 0; b < 32; ++b) w |= (xp[b] > 0.5f ? 1u : 0u) << b;
    xpk[j] = w;
  } else if (gid < 3072 + NW + 1) {       // initial state words (+ zero pad word)
    int w0 = gid - 3072;
    unsigned w = 0;
    if (w0 < NW)
      for (int j = 0; j < 32; ++j)
        w |= (init[w0 * 32 + j] > 0.5f ? 1u : 0u) << j;
    spk[w0] = w;
  }
}

// ---- one synchronous tick: src buffer -> dst buffer (compile-time offsets) ----
template<int SRCW, int DSTW>
__device__ __forceinline__ void do_tick(unsigned* sb, const unsigned* __restrict__ adjenc,
                                        const unsigned* __restrict__ lutpk, int t)
{
  for (int i = 0; i < 17; ++i) {
    int n = t + (i << 10);
    if (n < NTOT) {
      const uint4* ap = reinterpret_cast<const uint4*>(adjenc + ((size_t)n << 3));
      uint4 e0 = ap[0], e1 = ap[1];
      unsigned idx = 0, wv;
      #define GSTEP(ee) wv = sb[SRCW + ((ee & 0xFFFFu) >> 2)]; \
                        idx = (idx << 1) | ((wv >> (ee >> 16)) & 1u);
      GSTEP(e0.x) GSTEP(e0.y) GSTEP(e0.z) GSTEP(e0.w)
      GSTEP(e1.x) GSTEP(e1.y) GSTEP(e1.z) GSTEP(e1.w)
      #undef GSTEP
      unsigned lv = lutpk[(n << 3) + (idx >> 5)];
      unsigned nb = (lv >> (idx & 31u)) & 1u;
      unsigned long long bb = __ballot(nb);
      if ((t & 31) == 0)   // lane 0 writes low word, lane 32 writes high word
        sb[DSTW + (n >> 5)] = (unsigned)((t & 32) ? (bb >> 32) : bb);
    }
  }
  __syncthreads();
}

// ---- XOR-inject parity(x & w_col) into the first 512 state bits of buffer A ----
__device__ __forceinline__ void inject(unsigned* sb, const unsigned* __restrict__ wpk,
                                       unsigned xw, int c, int t)
{
  if (t < 512) {
    unsigned wb = wpk[c * 512 + t];
    unsigned bit = __popc(xw & wb) & 1u;
    unsigned long long bb = __ballot(bit);
    if ((t & 31) == 0)
      sb[t >> 5] ^= (unsigned)((t & 32) ? (bb >> 32) : bb);
  }
  __syncthreads();
}

// ---- main: one workgroup per batch, whole sim in LDS ----
__global__ __launch_bounds__(1024) void reservoir_main(
    const unsigned* __restrict__ adjenc, const unsigned* __restrict__ lutpk,
    const unsigned* __restrict__ wpk, const unsigned* __restrict__ xpk,
    const unsigned* __restrict__ spk, const float* __restrict__ Wout,
    const float* __restrict__ bout, float* __restrict__ out)
{
  __shared__ unsigned sb[LDSW];
  __shared__ float red[16 * N_OUT];
  const int t = threadIdx.x;
  const int m = blockIdx.x;

  for (int i = t; i < LDSW; i += 1024) sb[i] = (i < NW) ? spk[i] : 0u;
  __syncthreads();

  for (int s = 0; s < S; ++s) {
    inject(sb, wpk, xpk[(m * S + s) * 2 + 0], 0, t);
    do_tick<0, BOFF>(sb, adjenc, lutpk, t);
    do_tick<BOFF, 0>(sb, adjenc, lutpk, t);
    inject(sb, wpk, xpk[(m * S + s) * 2 + 1], 1, t);
    do_tick<0, BOFF>(sb, adjenc, lutpk, t);
    do_tick<BOFF, 0>(sb, adjenc, lutpk, t);
  }

  // readout: out[m,o] = sigmoid(b[o] + sum_r state[512+r] * Wout[o,r])
  float acc[N_OUT];
  #pragma unroll
  for (int o = 0; o < N_OUT; ++o) acc[o] = 0.f;
  for (int i = 0; i < 16; ++i) {
    int r = t + (i << 10);
    int p = I_N + r;
    unsigned w = sb[p >> 5];
    float bf = (float)((w >> (p & 31)) & 1u);
    #pragma unroll
    for (int o = 0; o < N_OUT; ++o)
      acc[o] += bf * Wout[o * R_N + r];
  }
  #pragma unroll
  for (int o = 0; o < N_OUT; ++o)
    for (int off = 32; off > 0; off >>= 1)
      acc[o] += __shfl_down(acc[o], off);
  if ((t & 63) == 0) {
    int wv = t >> 6;
    #pragma unroll
    for (int o = 0; o < N_OUT; ++o) red[wv * N_OUT + o] = acc[o];
  }
  __syncthreads();
  if (t < N_OUT) {
    float v = bout[t];
    for (int wv = 0; wv < 16; ++wv) v += red[wv * N_OUT + t];
    out[m * N_OUT + t] = 1.0f / (1.0f + expf(-v));
  }
}

extern "C" void kernel_launch(void* const* d_in, const int* in_sizes, int n_in,
                              void* d_out, int out_size, void* d_ws, size_t ws_size,
                              hipStream_t stream)
{
  const float* x    = (const float*)d_in[0];
  const float* w_in = (const float*)d_in[1];
  const int*   adj  = (const int*)d_in[2];
  // d_in[3] adj_mask: unused (recomputed from deg: mask[n][k] = k < deg[n])
  const int*   deg  = (const int*)d_in[4];
  const float* lut  = (const float*)d_in[5];
  // d_in[6] powers_of_2: implicit in bit order
  const float* init = (const float*)d_in[7];
  const float* Wout = (const float*)d_in[8];
  const float* bout = (const float*)d_in[9];

  char* ws = (char*)d_ws;
  unsigned* adjenc = (unsigned*)(ws + OFF_ADJ);
  unsigned* lutpk  = (unsigned*)(ws + OFF_LUT);
  unsigned* wpk    = (unsigned*)(ws + OFF_WPK);
  unsigned* xpk    = (unsigned*)(ws + OFF_XPK);
  unsigned* spk    = (unsigned*)(ws + OFF_SPK);

  hipLaunchKernelGGL(prep_big, dim3((NTOT * 8 + 255) / 256), dim3(256), 0, stream,
                     adj, deg, lut, adjenc, lutpk);
  hipLaunchKernelGGL(prep_small, dim3(15), dim3(256), 0, stream,
                     x, w_in, init, wpk, xpk, spk);
  hipLaunchKernelGGL(reservoir_main, dim3(M), dim3(1024), 0, stream,
                     adjenc, lutpk, wpk, xpk, spk, Wout, bout, (float*)d_out);
}